// Round 2
// baseline (281.887 us; speedup 1.0000x reference)
//
#include <hip/hip_runtime.h>
#include <hip/hip_bf16.h>

#define B_ROWS 4096
#define D_FEAT 512

__device__ inline float waveReduceSum(float v) {
#pragma unroll
    for (int off = 32; off > 0; off >>= 1) v += __shfl_xor(v, off);
    return v;
}

// ---- init workspace: posmax = 0.0f bits, negmin = 1e6f bits ----
__global__ __launch_bounds__(256) void init_ws_kernel(unsigned* __restrict__ posmax,
                                                      unsigned* __restrict__ negmin) {
    int i = blockIdx.x * 256 + threadIdx.x;
    posmax[i] = 0u;           // 0.0f
    negmin[i] = 0x49742400u;  // 1e6f
}

// ---- squared norms: one wave per row ----
__global__ __launch_bounds__(256) void sqnorm_kernel(const float* __restrict__ feat,
                                                     float* __restrict__ sqn) {
    int wave = threadIdx.x >> 6;
    int lane = threadIdx.x & 63;
    int row = blockIdx.x * 4 + wave;
    const float* p = feat + (size_t)row * D_FEAT;
    float4 a = *(const float4*)(p + lane * 4);
    float4 b = *(const float4*)(p + 256 + lane * 4);
    float s = a.x * a.x + a.y * a.y + a.z * a.z + a.w * a.w +
              b.x * b.x + b.y * b.y + b.z * b.z + b.w * b.w;
    s = waveReduceSum(s);
    if (lane == 0) sqn[row] = s;
}

// ---- focal + KD per-row, per-block partial sums (deterministic) ----
__global__ __launch_bounds__(256) void focal_kd_kernel(const float* __restrict__ logits,
                                                       const int* __restrict__ labels,
                                                       const float* __restrict__ soft,
                                                       float* __restrict__ fpart,
                                                       float* __restrict__ kpart) {
    int i = blockIdx.x * 256 + threadIdx.x;
    float l0 = logits[2 * i], l1 = logits[2 * i + 1];

    // focal (alpha=1, gamma=2)
    float m = fmaxf(l0, l1);
    float lse = m + logf(expf(l0 - m) + expf(l1 - m));
    float lp = (labels[i] ? l1 : l0) - lse;
    float ce = -lp;
    float pt = expf(lp);
    float om = 1.f - pt;
    float focal = om * om * ce;

    // KD (T=3)
    const float Tinv = 1.f / 3.f;
    float s0 = l0 * Tinv, s1 = l1 * Tinv;
    float ms = fmaxf(s0, s1);
    float lses = ms + logf(expf(s0 - ms) + expf(s1 - ms));
    float sl0 = s0 - lses, sl1 = s1 - lses;
    float t0 = logf(soft[2 * i] + 1e-8f) * Tinv;
    float t1 = logf(soft[2 * i + 1] + 1e-8f) * Tinv;
    float mt = fmaxf(t0, t1);
    float lset = mt + logf(expf(t0 - mt) + expf(t1 - mt));
    float tl0 = t0 - lset, tl1 = t1 - lset;
    float p0 = expf(tl0), p1 = expf(tl1);
    float kd = p0 * (tl0 - sl0) + p1 * (tl1 - sl1);

    float fs = waveReduceSum(focal);
    float ks = waveReduceSum(kd);
    __shared__ float sf[4], sk[4];
    int wave = threadIdx.x >> 6, lane = threadIdx.x & 63;
    if (lane == 0) { sf[wave] = fs; sk[wave] = ks; }
    __syncthreads();
    if (threadIdx.x == 0) {
        fpart[blockIdx.x] = sf[0] + sf[1] + sf[2] + sf[3];
        kpart[blockIdx.x] = sk[0] + sk[1] + sk[2] + sk[3];
    }
}

// ---- pairwise distance tile + batch-hard reductions ----
// 64x64 tile per block, fp32 LDS-tiled X·X^T, BK=16, 4x4 acc/thread.
__global__ __launch_bounds__(256) void pairwise_kernel(const float* __restrict__ feat,
                                                       const float* __restrict__ sqn,
                                                       const int* __restrict__ labels,
                                                       unsigned* __restrict__ posmax,
                                                       unsigned* __restrict__ negmin) {
    // stride 68 floats: keeps 16B alignment for float4 reads, writes ~2-way (free)
    __shared__ float As[16][68];
    __shared__ float Bs[16][68];
    const int ib = blockIdx.y, jb = blockIdx.x;
    const int tid = threadIdx.x;
    const int tm = tid >> 4, tn = tid & 15;
    const int lr = tid >> 2;            // 0..63 row within tile
    const int lc4 = (tid & 3) * 4;      // float4 slot within 16-wide k chunk

    const float* Ap = feat + (size_t)(ib * 64 + lr) * D_FEAT + lc4;
    const float* Bp = feat + (size_t)(jb * 64 + lr) * D_FEAT + lc4;

    float acc[4][4] = {};

    for (int kk = 0; kk < D_FEAT; kk += 16) {
        float4 a4 = *(const float4*)(Ap + kk);
        float4 b4 = *(const float4*)(Bp + kk);
        __syncthreads();
        As[lc4 + 0][lr] = a4.x; As[lc4 + 1][lr] = a4.y;
        As[lc4 + 2][lr] = a4.z; As[lc4 + 3][lr] = a4.w;
        Bs[lc4 + 0][lr] = b4.x; Bs[lc4 + 1][lr] = b4.y;
        Bs[lc4 + 2][lr] = b4.z; Bs[lc4 + 3][lr] = b4.w;
        __syncthreads();
#pragma unroll
        for (int k = 0; k < 16; ++k) {
            float4 av = *(const float4*)&As[k][tm * 4];
            float4 bv = *(const float4*)&Bs[k][tn * 4];
            float aa[4] = {av.x, av.y, av.z, av.w};
            float bb[4] = {bv.x, bv.y, bv.z, bv.w};
#pragma unroll
            for (int i = 0; i < 4; ++i)
#pragma unroll
                for (int j = 0; j < 4; ++j)
                    acc[i][j] = fmaf(aa[i], bb[j], acc[i][j]);
        }
    }

    // epilogue: distances + masked max/min, reduce over the 16 tn lanes
#pragma unroll
    for (int i = 0; i < 4; ++i) {
        int row = ib * 64 + tm * 4 + i;
        int labr = labels[row];
        float sqr = sqn[row];
        float pm = 0.f, nm = 1e6f;
#pragma unroll
        for (int j = 0; j < 4; ++j) {
            int col = jb * 64 + tn * 4 + j;
            float d2 = sqr + sqn[col] - 2.f * acc[i][j];
            float d = d2 > 0.f ? sqrtf(d2) : 0.f;
            bool same = (labr == labels[col]);
            if (same) {
                if (row != col) pm = fmaxf(pm, d);
            } else {
                nm = fminf(nm, d);
            }
        }
        // lanes sharing tm are 16 consecutive lanes; xor-reduce over tn
#pragma unroll
        for (int off = 1; off < 16; off <<= 1) {
            pm = fmaxf(pm, __shfl_xor(pm, off));
            nm = fminf(nm, __shfl_xor(nm, off));
        }
        if (tn == 0) {
            atomicMax(&posmax[row], __float_as_uint(pm));  // valid: d >= 0
            atomicMin(&negmin[row], __float_as_uint(nm));
        }
    }
}

// ---- final reduction + scalar combine (float32 outputs!) ----
__global__ __launch_bounds__(256) void finalize_kernel(const unsigned* __restrict__ posmax,
                                                       const unsigned* __restrict__ negmin,
                                                       const float* __restrict__ fpart,
                                                       const float* __restrict__ kpart,
                                                       float* __restrict__ out) {
    int tid = threadIdx.x;
    float sum_pr = 0.f, sum_v = 0.f;
    for (int i = tid; i < B_ROWS; i += 256) {
        float p = __uint_as_float(posmax[i]);
        float n = __uint_as_float(negmin[i]);
        float v = (p > 0.f) ? 1.f : 0.f;
        sum_pr += fmaxf(p - n + 0.3f, 0.f) * v;
        sum_v += v;
    }
    sum_pr = waveReduceSum(sum_pr);
    sum_v = waveReduceSum(sum_v);
    __shared__ float sp[4], sv[4];
    int wave = tid >> 6, lane = tid & 63;
    if (lane == 0) { sp[wave] = sum_pr; sv[wave] = sum_v; }
    __syncthreads();
    if (tid == 0) {
        float spr = sp[0] + sp[1] + sp[2] + sp[3];
        float svv = sv[0] + sv[1] + sv[2] + sv[3];
        float fsum = 0.f, ksum = 0.f;
        for (int b = 0; b < 16; ++b) { fsum += fpart[b]; ksum += kpart[b]; }
        float focal = fsum / 4096.f;
        float kd = ksum / 4096.f * 9.f;  // * T^2
        float triplet = (svv > 0.f) ? spr / fmaxf(svv, 1.f) : 0.f;
        float total = focal + 0.5f * triplet + kd;
        out[0] = total;
        out[1] = focal;
        out[2] = triplet;
        out[3] = kd;
    }
}

extern "C" void kernel_launch(void* const* d_in, const int* in_sizes, int n_in,
                              void* d_out, int out_size, void* d_ws, size_t ws_size,
                              hipStream_t stream) {
    const float* logits = (const float*)d_in[0];
    const float* feat   = (const float*)d_in[1];
    const int*   labels = (const int*)d_in[2];
    const float* soft   = (const float*)d_in[3];

    char* ws = (char*)d_ws;
    unsigned* posmax = (unsigned*)ws;                    // 4096 u32
    unsigned* negmin = (unsigned*)(ws + 16384);          // 4096 u32
    float*    sqn    = (float*)(ws + 32768);             // 4096 f32
    float*    fpart  = (float*)(ws + 49152);             // 16 f32
    float*    kpart  = (float*)(ws + 49152 + 64);        // 16 f32

    init_ws_kernel<<<16, 256, 0, stream>>>(posmax, negmin);
    sqnorm_kernel<<<1024, 256, 0, stream>>>(feat, sqn);
    focal_kd_kernel<<<16, 256, 0, stream>>>(logits, labels, soft, fpart, kpart);
    dim3 grid(64, 64);
    pairwise_kernel<<<grid, 256, 0, stream>>>(feat, sqn, labels, posmax, negmin);
    finalize_kernel<<<1, 256, 0, stream>>>(posmax, negmin, fpart, kpart,
                                           (float*)d_out);
}

// Round 3
// 72.373 us; speedup vs baseline: 3.8949x; 3.8949x over previous
//
#include <hip/hip_runtime.h>
#include <hip/hip_bf16.h>

#define B_ROWS 4096
#define D_FEAT 512

typedef short s16x8 __attribute__((ext_vector_type(8)));
typedef float f32x4 __attribute__((ext_vector_type(4)));

__device__ inline float waveReduceSum(float v) {
#pragma unroll
    for (int off = 32; off > 0; off >>= 1) v += __shfl_xor(v, off);
    return v;
}

// ---- init workspace: posmax = 0.0f bits, negmin = 1e6f bits ----
__global__ __launch_bounds__(256) void init_ws_kernel(unsigned* __restrict__ posmax,
                                                      unsigned* __restrict__ negmin) {
    int i = blockIdx.x * 256 + threadIdx.x;
    posmax[i] = 0u;           // 0.0f
    negmin[i] = 0x49742400u;  // 1e6f
}

// ---- convert fp32 features -> bf16 (row-major) + sqnorm of the ROUNDED values ----
// one wave per row; 8 elems per lane
__global__ __launch_bounds__(256) void convert_kernel(const float* __restrict__ feat,
                                                      short* __restrict__ featbf,
                                                      float* __restrict__ sqn) {
    int wave = threadIdx.x >> 6;
    int lane = threadIdx.x & 63;
    int row = blockIdx.x * 4 + wave;
    const float* p = feat + (size_t)row * D_FEAT + lane * 8;
    float4 a = *(const float4*)p;
    float4 b = *(const float4*)(p + 4);
    float vals[8] = {a.x, a.y, a.z, a.w, b.x, b.y, b.z, b.w};
    short out[8];
    float s = 0.f;
#pragma unroll
    for (int j = 0; j < 8; ++j) {
        __hip_bfloat16 h = __float2bfloat16(vals[j]);
        out[j] = *(short*)&h;
        float xb = __bfloat162float(h);
        s = fmaf(xb, xb, s);
    }
    *(s16x8*)(featbf + (size_t)row * D_FEAT + lane * 8) = *(s16x8*)out;
    s = waveReduceSum(s);
    if (lane == 0) sqn[row] = s;
}

// ---- focal + KD per-row, per-block partial sums (deterministic) ----
__global__ __launch_bounds__(256) void focal_kd_kernel(const float* __restrict__ logits,
                                                       const int* __restrict__ labels,
                                                       const float* __restrict__ soft,
                                                       float* __restrict__ fpart,
                                                       float* __restrict__ kpart) {
    int i = blockIdx.x * 256 + threadIdx.x;
    float l0 = logits[2 * i], l1 = logits[2 * i + 1];

    // focal (alpha=1, gamma=2)
    float m = fmaxf(l0, l1);
    float lse = m + logf(expf(l0 - m) + expf(l1 - m));
    float lp = (labels[i] ? l1 : l0) - lse;
    float ce = -lp;
    float pt = expf(lp);
    float om = 1.f - pt;
    float focal = om * om * ce;

    // KD (T=3)
    const float Tinv = 1.f / 3.f;
    float s0 = l0 * Tinv, s1 = l1 * Tinv;
    float ms = fmaxf(s0, s1);
    float lses = ms + logf(expf(s0 - ms) + expf(s1 - ms));
    float sl0 = s0 - lses, sl1 = s1 - lses;
    float t0 = logf(soft[2 * i] + 1e-8f) * Tinv;
    float t1 = logf(soft[2 * i + 1] + 1e-8f) * Tinv;
    float mt = fmaxf(t0, t1);
    float lset = mt + logf(expf(t0 - mt) + expf(t1 - mt));
    float tl0 = t0 - lset, tl1 = t1 - lset;
    float p0 = expf(tl0), p1 = expf(tl1);
    float kd = p0 * (tl0 - sl0) + p1 * (tl1 - sl1);

    float fs = waveReduceSum(focal);
    float ks = waveReduceSum(kd);
    __shared__ float sf[4], sk[4];
    int wave = threadIdx.x >> 6, lane = threadIdx.x & 63;
    if (lane == 0) { sf[wave] = fs; sk[wave] = ks; }
    __syncthreads();
    if (threadIdx.x == 0) {
        fpart[blockIdx.x] = sf[0] + sf[1] + sf[2] + sf[3];
        kpart[blockIdx.x] = sk[0] + sk[1] + sk[2] + sk[3];
    }
}

// ---- pairwise distances via bf16 MFMA + fused batch-hard reductions ----
// BM=BN=128, BK=32, 256 threads = 4 waves (2x2), wave tile 64x64 = 4x4 MFMA frags.
// LDS: [row][32 bf16] rows of 64B = 4 chunks of 16B; chunk index XOR-swizzled with
// ((row>>1)&3) so both ds_write (stage) and ds_read_b128 (frags) are 2-way (free).
__global__ __launch_bounds__(256) void pairwise_mfma_kernel(const short* __restrict__ featbf,
                                                            const float* __restrict__ sqn,
                                                            const int* __restrict__ labels,
                                                            unsigned* __restrict__ posmax,
                                                            unsigned* __restrict__ negmin) {
    __shared__ short As[128 * 32];
    __shared__ short Bs[128 * 32];
    const int tid = threadIdx.x;
    const int ib = blockIdx.y, jb = blockIdx.x;
    const int wid = tid >> 6, lane = tid & 63;
    const int wr = wid >> 1, wc = wid & 1;
    const int lo = lane & 15, hi = lane >> 4;

#define SLOT(r, c) ((r) * 4 + ((c) ^ (((r) >> 1) & 3)))

    // staging: thread t handles chunks (row=t>>2, c=t&3) and (row+64, c)
    const int srow = tid >> 2, sc = tid & 3;
    const short* Ag1 = featbf + (size_t)(ib * 128 + srow) * D_FEAT + sc * 8;
    const short* Ag2 = featbf + (size_t)(ib * 128 + srow + 64) * D_FEAT + sc * 8;
    const short* Bg1 = featbf + (size_t)(jb * 128 + srow) * D_FEAT + sc * 8;
    const short* Bg2 = featbf + (size_t)(jb * 128 + srow + 64) * D_FEAT + sc * 8;
    const int wa1 = SLOT(srow, sc) * 8;
    const int wa2 = SLOT(srow + 64, sc) * 8;

    // fragment read offsets
    int aoff[4], boff[4];
#pragma unroll
    for (int m = 0; m < 4; ++m) {
        int r_loc = wr * 64 + m * 16 + lo;
        aoff[m] = SLOT(r_loc, hi) * 8;
        int c_loc = wc * 64 + m * 16 + lo;
        boff[m] = SLOT(c_loc, hi) * 8;
    }

    f32x4 acc[4][4];
#pragma unroll
    for (int m = 0; m < 4; ++m)
#pragma unroll
        for (int n = 0; n < 4; ++n)
            acc[m][n] = (f32x4){0.f, 0.f, 0.f, 0.f};

    for (int kk = 0; kk < D_FEAT / 32; ++kk) {
        const int go = kk * 32;
        s16x8 a1 = *(const s16x8*)(Ag1 + go);
        s16x8 a2 = *(const s16x8*)(Ag2 + go);
        s16x8 b1 = *(const s16x8*)(Bg1 + go);
        s16x8 b2 = *(const s16x8*)(Bg2 + go);
        __syncthreads();
        *(s16x8*)(As + wa1) = a1;
        *(s16x8*)(As + wa2) = a2;
        *(s16x8*)(Bs + wa1) = b1;
        *(s16x8*)(Bs + wa2) = b2;
        __syncthreads();
        s16x8 af[4], bf_[4];
#pragma unroll
        for (int m = 0; m < 4; ++m) af[m] = *(const s16x8*)(As + aoff[m]);
#pragma unroll
        for (int n = 0; n < 4; ++n) bf_[n] = *(const s16x8*)(Bs + boff[n]);
#pragma unroll
        for (int m = 0; m < 4; ++m)
#pragma unroll
            for (int n = 0; n < 4; ++n)
                acc[m][n] = __builtin_amdgcn_mfma_f32_16x16x32_bf16(af[m], bf_[n],
                                                                   acc[m][n], 0, 0, 0);
    }

    // epilogue: d = sqrt(sqn_r + sqn_c - 2*dot), masked batch-hard max/min
    // C/D layout: col = lane&15, row = (lane>>4)*4 + reg. (Transpose-immune anyway:
    // d, masks, and diagonal exclusion are all symmetric.)
    int coln[4], labc[4];
    float sqc[4];
#pragma unroll
    for (int n = 0; n < 4; ++n) {
        coln[n] = jb * 128 + wc * 64 + n * 16 + lo;
        labc[n] = labels[coln[n]];
        sqc[n] = sqn[coln[n]];
    }
#pragma unroll
    for (int m = 0; m < 4; ++m) {
#pragma unroll
        for (int r = 0; r < 4; ++r) {
            int row_g = ib * 128 + wr * 64 + m * 16 + hi * 4 + r;
            int labr = labels[row_g];
            float sqr = sqn[row_g];
            float pm = 0.f, nm = 1e6f;
#pragma unroll
            for (int n = 0; n < 4; ++n) {
                float d2 = sqr + sqc[n] - 2.f * acc[m][n][r];
                float d = d2 > 0.f ? sqrtf(d2) : 0.f;
                bool same = (labr == labc[n]);
                if (same) {
                    if (row_g != coln[n]) pm = fmaxf(pm, d);
                } else {
                    nm = fminf(nm, d);
                }
            }
#pragma unroll
            for (int off = 1; off < 16; off <<= 1) {
                pm = fmaxf(pm, __shfl_xor(pm, off));
                nm = fminf(nm, __shfl_xor(nm, off));
            }
            if (lo == 0) {
                atomicMax(&posmax[row_g], __float_as_uint(pm));
                atomicMin(&negmin[row_g], __float_as_uint(nm));
            }
        }
    }
#undef SLOT
}

// ---- final reduction + scalar combine (float32 outputs) ----
__global__ __launch_bounds__(256) void finalize_kernel(const unsigned* __restrict__ posmax,
                                                       const unsigned* __restrict__ negmin,
                                                       const float* __restrict__ fpart,
                                                       const float* __restrict__ kpart,
                                                       float* __restrict__ out) {
    int tid = threadIdx.x;
    float sum_pr = 0.f, sum_v = 0.f;
    for (int i = tid; i < B_ROWS; i += 256) {
        float p = __uint_as_float(posmax[i]);
        float n = __uint_as_float(negmin[i]);
        float v = (p > 0.f) ? 1.f : 0.f;
        sum_pr += fmaxf(p - n + 0.3f, 0.f) * v;
        sum_v += v;
    }
    sum_pr = waveReduceSum(sum_pr);
    sum_v = waveReduceSum(sum_v);
    __shared__ float sp[4], sv[4];
    int wave = tid >> 6, lane = tid & 63;
    if (lane == 0) { sp[wave] = sum_pr; sv[wave] = sum_v; }
    __syncthreads();
    if (tid == 0) {
        float spr = sp[0] + sp[1] + sp[2] + sp[3];
        float svv = sv[0] + sv[1] + sv[2] + sv[3];
        float fsum = 0.f, ksum = 0.f;
        for (int b = 0; b < 16; ++b) { fsum += fpart[b]; ksum += kpart[b]; }
        float focal = fsum / 4096.f;
        float kd = ksum / 4096.f * 9.f;  // * T^2
        float triplet = (svv > 0.f) ? spr / fmaxf(svv, 1.f) : 0.f;
        float total = focal + 0.5f * triplet + kd;
        out[0] = total;
        out[1] = focal;
        out[2] = triplet;
        out[3] = kd;
    }
}

extern "C" void kernel_launch(void* const* d_in, const int* in_sizes, int n_in,
                              void* d_out, int out_size, void* d_ws, size_t ws_size,
                              hipStream_t stream) {
    const float* logits = (const float*)d_in[0];
    const float* feat   = (const float*)d_in[1];
    const int*   labels = (const int*)d_in[2];
    const float* soft   = (const float*)d_in[3];

    char* ws = (char*)d_ws;
    unsigned* posmax = (unsigned*)ws;                    // 4096 u32
    unsigned* negmin = (unsigned*)(ws + 16384);          // 4096 u32
    float*    sqn    = (float*)(ws + 32768);             // 4096 f32
    float*    fpart  = (float*)(ws + 49152);             // 16 f32
    float*    kpart  = (float*)(ws + 49152 + 256);       // 16 f32
    short*    featbf = (short*)(ws + 65536);             // 4096*512 bf16 = 4 MB

    init_ws_kernel<<<16, 256, 0, stream>>>(posmax, negmin);
    convert_kernel<<<1024, 256, 0, stream>>>(feat, featbf, sqn);
    focal_kd_kernel<<<16, 256, 0, stream>>>(logits, labels, soft, fpart, kpart);
    dim3 grid(32, 32);
    pairwise_mfma_kernel<<<grid, 256, 0, stream>>>(featbf, sqn, labels, posmax, negmin);
    finalize_kernel<<<1, 256, 0, stream>>>(posmax, negmin, fpart, kpart,
                                           (float*)d_out);
}